// Round 1
// baseline (1734.478 us; speedup 1.0000x reference)
//
#include <hip/hip_runtime.h>
#include <cmath>

// NonLocalBlock: GN -> QKV(1x1) -> softmax(QK^T/sqrt(C))V -> proj -> +x
// B=16, C=512, H=W=32, N=1024, G=32 groups (16 ch/group), fp32 in/out.
//
// Round 0: correct FP32 baseline.
//   k1 gn_stats  : per-(b,g) mean/rstd                -> ws.stats [512*2]
//   k2 qkv_gemm  : fused normalize + [N,C]x[C,3C] GEMM -> ws.qkv [B,N,3C]
//   k3 attn      : flash (QBLK=32,KBLK=32, D chunked 128), O overwrites q-slot
//   k4 proj      : [N,C]x[C,C] + bias + residual, LDS-transposed coalesced store
// ws needed: 4*(1024 + 16*1024*1536) bytes ~= 100.7 MB.

#define BB 16
#define CC 512
#define NN 1024
#define NG 32
#define CPG 16
#define QKVLD (3 * CC) // 1536
#define EPSV 1e-6f

// ---------------------------------------------------------------- gn stats
__global__ __launch_bounds__(256) void gn_stats_kernel(const float* __restrict__ x,
                                                       float* __restrict__ stats) {
  const int bg = blockIdx.x;            // b*32 + g ; group data is contiguous
  const int t  = threadIdx.x;
  const float4* xp = (const float4*)(x + (size_t)bg * (CPG * NN));
  float s = 0.f, ss = 0.f;
  #pragma unroll
  for (int it = 0; it < (CPG * NN / 4) / 256; ++it) {
    float4 v = xp[it * 256 + t];
    s  += v.x + v.y + v.z + v.w;
    ss += v.x * v.x + v.y * v.y + v.z * v.z + v.w * v.w;
  }
  #pragma unroll
  for (int off = 32; off >= 1; off >>= 1) {
    s  += __shfl_down(s, off);
    ss += __shfl_down(ss, off);
  }
  __shared__ float red[4][2];
  if ((t & 63) == 0) { red[t >> 6][0] = s; red[t >> 6][1] = ss; }
  __syncthreads();
  if (t == 0) {
    s  = red[0][0] + red[1][0] + red[2][0] + red[3][0];
    ss = red[0][1] + red[1][1] + red[2][1] + red[3][1];
    const float inv  = 1.f / (float)(CPG * NN);
    const float mean = s * inv;
    const float var  = ss * inv - mean * mean;
    stats[bg * 2 + 0] = mean;
    stats[bg * 2 + 1] = rsqrtf(var + EPSV);
  }
}

// ------------------------------------------------------------- QKV GEMM
// qkv[b][n][o] = sum_c xn[b][c][n] * w[o][c] + bias[o]
// 64x64 tile, BK=16, 256 thr, 4x4 micro-tile. A normalized on load.
__global__ __launch_bounds__(256) void qkv_gemm_kernel(const float* __restrict__ x,
                                                       const float* __restrict__ stats,
                                                       const float* __restrict__ gamma,
                                                       const float* __restrict__ beta,
                                                       const float* __restrict__ w,
                                                       const float* __restrict__ bias,
                                                       float* __restrict__ qkv) {
  __shared__ float As[16][68]; // [k][m], stride 68 keeps float4 alignment
  __shared__ float Bs[16][68]; // [k][o]
  const int b  = blockIdx.z;
  const int m0 = blockIdx.x * 64;
  const int o0 = blockIdx.y * 64;
  const int t  = threadIdx.x;
  const int ty = t >> 4, tx = t & 15;
  float acc[4][4] = {};
  const float* xb = x + (size_t)b * CC * NN;
  const float* st = stats + b * NG * 2;

  for (int k0 = 0; k0 < CC; k0 += 16) {
    { // A tile: x rows are contiguous along n -> coalesced 256B per row
      const int col = t & 63, r = t >> 6;
      #pragma unroll
      for (int i = 0; i < 4; ++i) {
        const int k = r * 4 + i;
        const int c = k0 + k;
        const float mean = st[(c >> 4) * 2 + 0];
        const float rstd = st[(c >> 4) * 2 + 1];
        const float v = xb[(size_t)c * NN + m0 + col];
        As[k][col] = (v - mean) * rstd * gamma[c] + beta[c];
      }
      // B tile: float4 along c per output row
      const int j = t & 63, kb = (t >> 6) * 4;
      const float4 wv = *(const float4*)&w[(size_t)(o0 + j) * CC + k0 + kb];
      Bs[kb + 0][j] = wv.x; Bs[kb + 1][j] = wv.y;
      Bs[kb + 2][j] = wv.z; Bs[kb + 3][j] = wv.w;
    }
    __syncthreads();
    #pragma unroll
    for (int k = 0; k < 16; ++k) {
      const float4 av = *(const float4*)&As[k][ty * 4];
      const float4 bv = *(const float4*)&Bs[k][tx * 4];
      const float ar[4] = {av.x, av.y, av.z, av.w};
      const float br[4] = {bv.x, bv.y, bv.z, bv.w};
      #pragma unroll
      for (int i = 0; i < 4; ++i)
        #pragma unroll
        for (int j = 0; j < 4; ++j)
          acc[i][j] += ar[i] * br[j];
    }
    __syncthreads();
  }

  float* outp = qkv + (size_t)b * NN * QKVLD;
  const float4 bv = *(const float4*)&bias[o0 + tx * 4];
  const float br[4] = {bv.x, bv.y, bv.z, bv.w};
  #pragma unroll
  for (int i = 0; i < 4; ++i) {
    const int n = m0 + ty * 4 + i;
    float4 o;
    o.x = acc[i][0] + br[0];
    o.y = acc[i][1] + br[1];
    o.z = acc[i][2] + br[2];
    o.w = acc[i][3] + br[3];
    *(float4*)&outp[(size_t)n * QKVLD + o0 + tx * 4] = o;
  }
}

// ------------------------------------------------------------- attention
// One block per (batch, 32-row q-tile). Flash over 32-row K/V tiles,
// D=512 streamed through LDS in 128-col chunks. O accumulates in regs
// (thread t owns row t>>3, d-lanes (t&7)*16 within each 128-chunk).
// Final O/l overwrites the q slot (each block owns its q rows exclusively).
__global__ __launch_bounds__(256) void attn_kernel(float* __restrict__ qkv) {
  const int b   = blockIdx.y;
  const int q0  = blockIdx.x * 32;
  const int t   = threadIdx.x;
  const int ir  = t >> 3;  // 0..31
  const int sub = t & 7;   // 0..7
  float* base = qkv + (size_t)b * NN * QKVLD;
  const float scale = 0.04419417382415922f; // 1/sqrt(512)

  __shared__ float Qc[32][132];
  __shared__ float KVc[32][132];
  __shared__ float Sl[32][36];

  float acc[4][16];
  #pragma unroll
  for (int a = 0; a < 4; ++a)
    #pragma unroll
    for (int u = 0; u < 16; ++u) acc[a][u] = 0.f;
  float m_r = -INFINITY, l_r = 0.f;

  const int si = (t >> 4) * 2; // S-phase 2x2 micro-tile rows
  const int sj = (t & 15) * 2;

  for (int k0 = 0; k0 < NN; k0 += 32) {
    // ---- S = Q K^T (accumulate over 4 chunks of 128 c) ----
    float s2[2][2] = {};
    for (int c0 = 0; c0 < CC; c0 += 128) {
      {
        const float* qsrc = base + (size_t)(q0 + ir) * QKVLD + c0 + sub * 16;
        const float* ksrc = base + (size_t)(k0 + ir) * QKVLD + CC + c0 + sub * 16;
        const float4 qv0 = *(const float4*)(qsrc + 0);
        const float4 qv1 = *(const float4*)(qsrc + 4);
        const float4 qv2 = *(const float4*)(qsrc + 8);
        const float4 qv3 = *(const float4*)(qsrc + 12);
        const float4 kv0 = *(const float4*)(ksrc + 0);
        const float4 kv1 = *(const float4*)(ksrc + 4);
        const float4 kv2 = *(const float4*)(ksrc + 8);
        const float4 kv3 = *(const float4*)(ksrc + 12);
        *(float4*)&Qc[ir][sub * 16 + 0]  = qv0;
        *(float4*)&Qc[ir][sub * 16 + 4]  = qv1;
        *(float4*)&Qc[ir][sub * 16 + 8]  = qv2;
        *(float4*)&Qc[ir][sub * 16 + 12] = qv3;
        *(float4*)&KVc[ir][sub * 16 + 0]  = kv0;
        *(float4*)&KVc[ir][sub * 16 + 4]  = kv1;
        *(float4*)&KVc[ir][sub * 16 + 8]  = kv2;
        *(float4*)&KVc[ir][sub * 16 + 12] = kv3;
      }
      __syncthreads();
      #pragma unroll 8
      for (int cc = 0; cc < 128; cc += 4) {
        const float4 qa = *(const float4*)&Qc[si][cc];
        const float4 qb = *(const float4*)&Qc[si + 1][cc];
        const float4 ka = *(const float4*)&KVc[sj][cc];
        const float4 kb = *(const float4*)&KVc[sj + 1][cc];
        s2[0][0] += qa.x * ka.x + qa.y * ka.y + qa.z * ka.z + qa.w * ka.w;
        s2[0][1] += qa.x * kb.x + qa.y * kb.y + qa.z * kb.z + qa.w * kb.w;
        s2[1][0] += qb.x * ka.x + qb.y * ka.y + qb.z * ka.z + qb.w * ka.w;
        s2[1][1] += qb.x * kb.x + qb.y * kb.y + qb.z * kb.z + qb.w * kb.w;
      }
      __syncthreads();
    }
    Sl[si][sj]         = s2[0][0];
    Sl[si][sj + 1]     = s2[0][1];
    Sl[si + 1][sj]     = s2[1][0];
    Sl[si + 1][sj + 1] = s2[1][1];
    __syncthreads();

    // ---- online softmax (thread handles row ir, cols sub*4..sub*4+3) ----
    float sv[4];
    float pm = -INFINITY;
    #pragma unroll
    for (int u = 0; u < 4; ++u) {
      sv[u] = Sl[ir][sub * 4 + u] * scale;
      pm = fmaxf(pm, sv[u]);
    }
    pm = fmaxf(pm, __shfl_xor(pm, 1));
    pm = fmaxf(pm, __shfl_xor(pm, 2));
    pm = fmaxf(pm, __shfl_xor(pm, 4));
    const float m_new = fmaxf(m_r, pm);
    const float corr  = __expf(m_r - m_new); // 0 when m_r = -inf
    float ps = 0.f;
    #pragma unroll
    for (int u = 0; u < 4; ++u) {
      const float p = __expf(sv[u] - m_new);
      Sl[ir][sub * 4 + u] = p;
      ps += p;
    }
    ps += __shfl_xor(ps, 1);
    ps += __shfl_xor(ps, 2);
    ps += __shfl_xor(ps, 4);
    l_r = l_r * corr + ps;
    m_r = m_new;
    #pragma unroll
    for (int a = 0; a < 4; ++a)
      #pragma unroll
      for (int u = 0; u < 16; ++u) acc[a][u] *= corr;
    __syncthreads();

    // ---- O += P V (4 chunks of 128 d) ----
    #pragma unroll
    for (int ci = 0; ci < 4; ++ci) {
      {
        const float* vsrc = base + (size_t)(k0 + ir) * QKVLD + 2 * CC + ci * 128 + sub * 16;
        const float4 v0 = *(const float4*)(vsrc + 0);
        const float4 v1 = *(const float4*)(vsrc + 4);
        const float4 v2 = *(const float4*)(vsrc + 8);
        const float4 v3 = *(const float4*)(vsrc + 12);
        *(float4*)&KVc[ir][sub * 16 + 0]  = v0;
        *(float4*)&KVc[ir][sub * 16 + 4]  = v1;
        *(float4*)&KVc[ir][sub * 16 + 8]  = v2;
        *(float4*)&KVc[ir][sub * 16 + 12] = v3;
      }
      __syncthreads();
      #pragma unroll 4
      for (int j = 0; j < 32; ++j) {
        const float p = Sl[ir][j];
        const float4 v0 = *(const float4*)&KVc[j][sub * 16 + 0];
        const float4 v1 = *(const float4*)&KVc[j][sub * 16 + 4];
        const float4 v2 = *(const float4*)&KVc[j][sub * 16 + 8];
        const float4 v3 = *(const float4*)&KVc[j][sub * 16 + 12];
        acc[ci][0]  += p * v0.x; acc[ci][1]  += p * v0.y;
        acc[ci][2]  += p * v0.z; acc[ci][3]  += p * v0.w;
        acc[ci][4]  += p * v1.x; acc[ci][5]  += p * v1.y;
        acc[ci][6]  += p * v1.z; acc[ci][7]  += p * v1.w;
        acc[ci][8]  += p * v2.x; acc[ci][9]  += p * v2.y;
        acc[ci][10] += p * v2.z; acc[ci][11] += p * v2.w;
        acc[ci][12] += p * v3.x; acc[ci][13] += p * v3.y;
        acc[ci][14] += p * v3.z; acc[ci][15] += p * v3.w;
      }
      __syncthreads();
    }
  }

  // ---- write y = O/l over the q slot ----
  const float inv_l = 1.f / l_r;
  #pragma unroll
  for (int ci = 0; ci < 4; ++ci) {
    float* dst = base + (size_t)(q0 + ir) * QKVLD + ci * 128 + sub * 16;
    #pragma unroll
    for (int u = 0; u < 16; u += 4) {
      float4 o;
      o.x = acc[ci][u + 0] * inv_l;
      o.y = acc[ci][u + 1] * inv_l;
      o.z = acc[ci][u + 2] * inv_l;
      o.w = acc[ci][u + 3] * inv_l;
      *(float4*)(dst + u) = o;
    }
  }
}

// ------------------------------------------------------- proj + residual
// out[b][oc][n] = x[b][oc][n] + b_proj[oc] + sum_c y[b][n][c]*w_proj[oc][c]
__global__ __launch_bounds__(256) void proj_kernel(const float* __restrict__ x,
                                                   const float* __restrict__ y, // qkv q-slot, ld=1536
                                                   const float* __restrict__ w,
                                                   const float* __restrict__ bias,
                                                   float* __restrict__ out) {
  __shared__ float As[16][68]; // [k][m]
  __shared__ float Bs[16][68]; // [k][oc]
  __shared__ float Ct[64][68]; // transpose staging [oc][m]
  const int b  = blockIdx.z;
  const int m0 = blockIdx.x * 64; // n
  const int o0 = blockIdx.y * 64; // out channel
  const int t  = threadIdx.x;
  const int ty = t >> 4, tx = t & 15;
  float acc[4][4] = {};
  const float* yb = y + (size_t)b * NN * QKVLD;

  for (int k0 = 0; k0 < CC; k0 += 16) {
    {
      const int m = t & 63, kb = (t >> 6) * 4;
      const float4 av = *(const float4*)&yb[(size_t)(m0 + m) * QKVLD + k0 + kb];
      As[kb + 0][m] = av.x; As[kb + 1][m] = av.y;
      As[kb + 2][m] = av.z; As[kb + 3][m] = av.w;
      const float4 wv = *(const float4*)&w[(size_t)(o0 + m) * CC + k0 + kb];
      Bs[kb + 0][m] = wv.x; Bs[kb + 1][m] = wv.y;
      Bs[kb + 2][m] = wv.z; Bs[kb + 3][m] = wv.w;
    }
    __syncthreads();
    #pragma unroll
    for (int k = 0; k < 16; ++k) {
      const float4 av = *(const float4*)&As[k][ty * 4];
      const float4 bv = *(const float4*)&Bs[k][tx * 4];
      const float ar[4] = {av.x, av.y, av.z, av.w};
      const float br[4] = {bv.x, bv.y, bv.z, bv.w};
      #pragma unroll
      for (int i = 0; i < 4; ++i)
        #pragma unroll
        for (int j = 0; j < 4; ++j)
          acc[i][j] += ar[i] * br[j];
    }
    __syncthreads();
  }

  #pragma unroll
  for (int i = 0; i < 4; ++i)
    #pragma unroll
    for (int j = 0; j < 4; ++j)
      Ct[tx * 4 + j][ty * 4 + i] = acc[i][j];
  __syncthreads();

  const int col = t & 63, rq = t >> 6;
  const float* xb = x + (size_t)b * CC * NN;
  float* ob = out + (size_t)b * CC * NN;
  #pragma unroll
  for (int s = 0; s < 16; ++s) {
    const int ol = rq * 16 + s;
    const int oc = o0 + ol;
    const size_t idx = (size_t)oc * NN + m0 + col;
    ob[idx] = Ct[ol][col] + bias[oc] + xb[idx];
  }
}

// ---------------------------------------------------------------- launch
extern "C" void kernel_launch(void* const* d_in, const int* in_sizes, int n_in,
                              void* d_out, int out_size, void* d_ws, size_t ws_size,
                              hipStream_t stream) {
  const float* x      = (const float*)d_in[0];
  const float* gamma  = (const float*)d_in[1];
  const float* beta   = (const float*)d_in[2];
  const float* w_qkv  = (const float*)d_in[3];
  const float* b_qkv  = (const float*)d_in[4];
  const float* w_proj = (const float*)d_in[5];
  const float* b_proj = (const float*)d_in[6];
  float* out = (float*)d_out;

  float* stats = (float*)d_ws;          // [B*NG*2]
  float* qkv   = stats + 1024;          // [B][N][3C] fp32, 100.7 MB

  hipLaunchKernelGGL(gn_stats_kernel, dim3(BB * NG), dim3(256), 0, stream, x, stats);
  hipLaunchKernelGGL(qkv_gemm_kernel, dim3(NN / 64, QKVLD / 64, BB), dim3(256), 0, stream,
                     x, stats, gamma, beta, w_qkv, b_qkv, qkv);
  hipLaunchKernelGGL(attn_kernel, dim3(NN / 32, BB), dim3(256), 0, stream, qkv);
  hipLaunchKernelGGL(proj_kernel, dim3(NN / 64, CC / 64, BB), dim3(256), 0, stream,
                     x, qkv, w_proj, b_proj, out);
}

// Round 6
// 688.028 us; speedup vs baseline: 2.5209x; 2.5209x over previous
//
#include <hip/hip_runtime.h>
#include <cmath>

// NonLocalBlock: GN -> QKV(1x1) -> softmax(QK^T/sqrt(C))V -> proj -> +x
// B=16, C=512, H=W=32, N=1024, G=32 (16 ch/group), fp32 in/out.
//
// Round 5 (= round 1..4 design, unchanged; never yet benched): bf16-MFMA flash attention.
//   k1 gn_stats  : per-(b,g) mean/rstd -> ws.stats
//   k2 qkv_gemm  : fp32 compute, fused GN; writes bf16 planes:
//                  qbuf [b][n][512] (pre-scaled by 1/sqrt(C)),
//                  kbuf [b][n][512], vbuf [b][512][n] (transposed for PV B-op)
//   k3 attn_mfma : flash, QBLK=32/KBLK=128, mfma_f32_32x32x16_bf16,
//                  global_load_lds w/ XOR-preswizzle, XCD-grouped blocks
//   k4 proj      : fp32 compute, reads bf16 y, +bias +residual
// ws: 4KB stats + 4 x 16MB bf16 planes = ~64MB.

#define BB 16
#define CC 512
#define NN 1024
#define NG 32
#define CPG 16
#define EPSV 1e-6f
#define SCALE 0.044194173824159216f  // 1/sqrt(512)

typedef __attribute__((ext_vector_type(8))) short short8;
typedef __attribute__((ext_vector_type(16))) float f32x16;

static __device__ __forceinline__ ushort f2bf(float f) {
  uint32_t x = __float_as_uint(f);
  uint32_t r = (x + 0x7fffu + ((x >> 16) & 1u)) >> 16;  // RNE
  return (ushort)r;
}
static __device__ __forceinline__ float bf2f(ushort u) {
  return __uint_as_float(((uint32_t)u) << 16);
}

// ---------------------------------------------------------------- gn stats
__global__ __launch_bounds__(256) void gn_stats_kernel(const float* __restrict__ x,
                                                       float* __restrict__ stats) {
  const int bg = blockIdx.x;
  const int t  = threadIdx.x;
  const float4* xp = (const float4*)(x + (size_t)bg * (CPG * NN));
  float s = 0.f, ss = 0.f;
  #pragma unroll
  for (int it = 0; it < (CPG * NN / 4) / 256; ++it) {
    float4 v = xp[it * 256 + t];
    s  += v.x + v.y + v.z + v.w;
    ss += v.x * v.x + v.y * v.y + v.z * v.z + v.w * v.w;
  }
  #pragma unroll
  for (int off = 32; off >= 1; off >>= 1) {
    s  += __shfl_down(s, off);
    ss += __shfl_down(ss, off);
  }
  __shared__ float red[4][2];
  if ((t & 63) == 0) { red[t >> 6][0] = s; red[t >> 6][1] = ss; }
  __syncthreads();
  if (t == 0) {
    s  = red[0][0] + red[1][0] + red[2][0] + red[3][0];
    ss = red[0][1] + red[1][1] + red[2][1] + red[3][1];
    const float inv  = 1.f / (float)(CPG * NN);
    const float mean = s * inv;
    const float var  = ss * inv - mean * mean;
    stats[bg * 2 + 0] = mean;
    stats[bg * 2 + 1] = rsqrtf(var + EPSV);
  }
}

// ------------------------------------------------------------- QKV GEMM (fp32 -> bf16 planes)
__global__ __launch_bounds__(256) void qkv_gemm_kernel(const float* __restrict__ x,
                                                       const float* __restrict__ stats,
                                                       const float* __restrict__ gamma,
                                                       const float* __restrict__ beta,
                                                       const float* __restrict__ w,
                                                       const float* __restrict__ bias,
                                                       ushort* __restrict__ qbuf,
                                                       ushort* __restrict__ kbuf,
                                                       ushort* __restrict__ vbuf) {
  __shared__ float As[16][68];
  __shared__ float Bs[16][68];
  __shared__ float Ct[64][68];  // v-transpose staging
  const int b  = blockIdx.z;
  const int m0 = blockIdx.x * 64;       // n
  const int o0 = blockIdx.y * 64;       // out channel of 1536
  const int t  = threadIdx.x;
  const int ty = t >> 4, tx = t & 15;
  float acc[4][4] = {};
  const float* xb = x + (size_t)b * CC * NN;
  const float* st = stats + b * NG * 2;

  for (int k0 = 0; k0 < CC; k0 += 16) {
    {
      const int col = t & 63, r = t >> 6;
      #pragma unroll
      for (int i = 0; i < 4; ++i) {
        const int k = r * 4 + i;
        const int c = k0 + k;
        const float mean = st[(c >> 4) * 2 + 0];
        const float rstd = st[(c >> 4) * 2 + 1];
        const float v = xb[(size_t)c * NN + m0 + col];
        As[k][col] = (v - mean) * rstd * gamma[c] + beta[c];
      }
      const int j = t & 63, kb = (t >> 6) * 4;
      const float4 wv = *(const float4*)&w[(size_t)(o0 + j) * CC + k0 + kb];
      Bs[kb + 0][j] = wv.x; Bs[kb + 1][j] = wv.y;
      Bs[kb + 2][j] = wv.z; Bs[kb + 3][j] = wv.w;
    }
    __syncthreads();
    #pragma unroll
    for (int k = 0; k < 16; ++k) {
      const float4 av = *(const float4*)&As[k][ty * 4];
      const float4 bv = *(const float4*)&Bs[k][tx * 4];
      const float ar[4] = {av.x, av.y, av.z, av.w};
      const float br[4] = {bv.x, bv.y, bv.z, bv.w};
      #pragma unroll
      for (int i = 0; i < 4; ++i)
        #pragma unroll
        for (int j = 0; j < 4; ++j)
          acc[i][j] += ar[i] * br[j];
    }
    __syncthreads();
  }

  const float4 bv = *(const float4*)&bias[o0 + tx * 4];
  const float br[4] = {bv.x, bv.y, bv.z, bv.w};

  if (o0 < 1024) {
    // q or k plane: [b][n][512], q pre-scaled by 1/sqrt(C)
    ushort* plane = (o0 < 512) ? (qbuf + (size_t)b * NN * CC)
                               : (kbuf + (size_t)b * NN * CC);
    const int oo = (o0 < 512) ? o0 : (o0 - 512);
    const float sc = (o0 < 512) ? SCALE : 1.f;
    #pragma unroll
    for (int i = 0; i < 4; ++i) {
      const int n = m0 + ty * 4 + i;
      ushort4 pk;
      pk.x = f2bf((acc[i][0] + br[0]) * sc);
      pk.y = f2bf((acc[i][1] + br[1]) * sc);
      pk.z = f2bf((acc[i][2] + br[2]) * sc);
      pk.w = f2bf((acc[i][3] + br[3]) * sc);
      *(ushort4*)&plane[(size_t)n * CC + oo + tx * 4] = pk;
    }
  } else {
    // v plane transposed: [b][512 d][1024 n]
    #pragma unroll
    for (int i = 0; i < 4; ++i)
      #pragma unroll
      for (int j = 0; j < 4; ++j)
        Ct[tx * 4 + j][ty * 4 + i] = acc[i][j] + br[j];
    __syncthreads();
    ushort* vb = vbuf + (size_t)b * CC * NN;
    const int col = t & 63, rq = t >> 6;
    #pragma unroll
    for (int s = 0; s < 16; ++s) {
      const int ol = rq * 16 + s;
      const int d  = o0 - 1024 + ol;
      vb[(size_t)d * NN + m0 + col] = f2bf(Ct[ol][col]);
    }
  }
}

// ------------------------------------------------------------- flash attention (MFMA)
// 256 thr / 4 waves. QBLK=32 rows per block, KBLK=128 keys per iter.
// Wave w: QK^T -> S cols [w*32, w*32+32); PV -> d-cols {ci*128 + w*32}.
// K chunk LDS [128 k][128 c] bf16, V chunk [128 d][128 k] bf16, single buffer,
// XOR swizzle ((row&15)<<4) applied via pre-swizzled global_load_lds source
// (linear LDS dest + inverse-swizzled global src + swizzled ds_read — rule #21).
__device__ __forceinline__ void stage_chunk(const ushort* __restrict__ src, int stride,
                                            ushort* kv, int w, int lane) {
  #pragma unroll
  for (int i = 0; i < 8; ++i) {
    const int base = (i * 4 + w) * 1024;                 // bytes, wave-uniform
    const int r    = (base >> 8) + (lane >> 4);          // row 0..127
    const int sx   = ((lane & 15) << 4) ^ ((r & 15) << 4);
    __builtin_amdgcn_global_load_lds(
        (const __attribute__((address_space(1))) void*)(src + (size_t)r * stride + (sx >> 1)),
        (__attribute__((address_space(3))) void*)(kv + (base >> 1)),
        16, 0, 0);
  }
}

__global__ __launch_bounds__(256, 2) void attn_mfma_kernel(const ushort* __restrict__ qb,
                                                           const ushort* __restrict__ kb,
                                                           const ushort* __restrict__ vb,
                                                           ushort* __restrict__ yb) {
  __shared__ ushort KV[128 * 128];   // 32KB chunk
  __shared__ float  Sl[32][132];
  __shared__ ushort Pl[32][136];
  __shared__ float  m_s[32], l_s[32], c_s[32];

  // XCD-grouped swizzle: XCD x handles batches {2x, 2x+1} -> K/V fits its 4MB L2
  const int orig = blockIdx.x + blockIdx.y * gridDim.x;   // 0..511
  const int wg   = (orig & 7) * 64 + (orig >> 3);
  const int b    = wg >> 5;
  const int q0   = (wg & 31) * 32;
  const int t    = threadIdx.x;
  const int lane = t & 63;
  const int w    = t >> 6;
  const int lr   = lane & 31;
  const int lh   = lane >> 5;

  const ushort* qbb = qb + (size_t)b * NN * CC;
  const ushort* kbb = kb + (size_t)b * NN * CC;
  const ushort* vbb = vb + (size_t)b * CC * NN;
  ushort* ybb = yb + (size_t)b * NN * CC;

  if (t < 32) { m_s[t] = -INFINITY; l_s[t] = 0.f; }

  // Q resident: lane holds row q0+lr, frag f covers c = f*16 + lh*8 .. +7
  short8 qf[32];
  #pragma unroll
  for (int f = 0; f < 32; ++f)
    qf[f] = *(const short8*)&qbb[(size_t)(q0 + lr) * CC + f * 16 + lh * 8];

  f32x16 Ov[4];
  #pragma unroll
  for (int ci = 0; ci < 4; ++ci)
    #pragma unroll
    for (int rg = 0; rg < 16; ++rg) Ov[ci][rg] = 0.f;

  for (int k0 = 0; k0 < NN; k0 += 128) {
    // ---- S = Q K^T over 4 c-chunks of 128 ----
    f32x16 S;
    #pragma unroll
    for (int rg = 0; rg < 16; ++rg) S[rg] = 0.f;
    #pragma unroll  // keep qf[] indices compile-time constant (rule #20)
    for (int cc = 0; cc < 4; ++cc) {
      __syncthreads();                                   // protect prev KV readers
      stage_chunk(kbb + (size_t)k0 * CC + cc * 128, CC, KV, w, lane);
      __syncthreads();                                   // vmcnt drained
      const int krow = w * 32 + lr;
      #pragma unroll
      for (int cs = 0; cs < 8; ++cs) {
        const int boff = (krow << 8) + ((((cs * 16 + lh * 8) << 1)) ^ ((krow & 15) << 4));
        short8 kf = *(const short8*)((const char*)KV + boff);
        S = __builtin_amdgcn_mfma_f32_32x32x16_bf16(qf[cc * 8 + cs], kf, S, 0, 0, 0);
      }
    }
    // ---- S -> LDS (C layout: col=lane&31, row=(rg&3)+8*(rg>>2)+4*lh) ----
    #pragma unroll
    for (int rg = 0; rg < 16; ++rg) {
      const int r = (rg & 3) + 8 * (rg >> 2) + 4 * lh;
      Sl[r][w * 32 + lr] = S[rg];
    }
    __syncthreads();
    // ---- online softmax: row = t>>3, 8 threads x 16 cols each ----
    {
      const int row = t >> 3, seg = t & 7;
      float v[16];
      float mx = -INFINITY;
      #pragma unroll
      for (int u = 0; u < 16; ++u) { v[u] = Sl[row][seg * 16 + u]; mx = fmaxf(mx, v[u]); }
      mx = fmaxf(mx, __shfl_xor(mx, 1));
      mx = fmaxf(mx, __shfl_xor(mx, 2));
      mx = fmaxf(mx, __shfl_xor(mx, 4));
      const float mo = m_s[row];
      const float mn = fmaxf(mo, mx);
      const float corr = __expf(mo - mn);                // 0 on first tile
      float ps = 0.f;
      #pragma unroll
      for (int u = 0; u < 16; ++u) {
        const float p = __expf(v[u] - mn);
        ps += p;
        Pl[row][seg * 16 + u] = f2bf(p);
      }
      ps += __shfl_xor(ps, 1);
      ps += __shfl_xor(ps, 2);
      ps += __shfl_xor(ps, 4);
      if (seg == 0) {
        c_s[row] = corr;
        m_s[row] = mn;
        l_s[row] = l_s[row] * corr + ps;
      }
    }
    __syncthreads();
    // ---- rescale O ----
    float cr[16];
    #pragma unroll
    for (int rg = 0; rg < 16; ++rg) cr[rg] = c_s[(rg & 3) + 8 * (rg >> 2) + 4 * lh];
    #pragma unroll
    for (int ci = 0; ci < 4; ++ci)
      #pragma unroll
      for (int rg = 0; rg < 16; ++rg) Ov[ci][rg] *= cr[rg];
    // ---- O += P V over 4 d-chunks of 128 ----
    #pragma unroll  // keep Ov[] indices compile-time constant (rule #20)
    for (int ci = 0; ci < 4; ++ci) {
      __syncthreads();
      stage_chunk(vbb + (size_t)(ci * 128) * NN + k0, NN, KV, w, lane);
      __syncthreads();
      const int vrow = w * 32 + lr;
      #pragma unroll
      for (int ks = 0; ks < 8; ++ks) {
        short8 pf = *(const short8*)((const char*)Pl + lr * 272 + ks * 32 + lh * 16);
        const int boff = (vrow << 8) + ((((ks * 16 + lh * 8) << 1)) ^ ((vrow & 15) << 4));
        short8 vf = *(const short8*)((const char*)KV + boff);
        Ov[ci] = __builtin_amdgcn_mfma_f32_32x32x16_bf16(pf, vf, Ov[ci], 0, 0, 0);
      }
    }
  }

  // ---- epilogue: y = O / l -> bf16 [n][512] ----
  float invl[16];
  #pragma unroll
  for (int rg = 0; rg < 16; ++rg) invl[rg] = 1.f / l_s[(rg & 3) + 8 * (rg >> 2) + 4 * lh];
  #pragma unroll
  for (int ci = 0; ci < 4; ++ci)
    #pragma unroll
    for (int rg = 0; rg < 16; ++rg) {
      const int r = (rg & 3) + 8 * (rg >> 2) + 4 * lh;
      const int d = ci * 128 + w * 32 + lr;
      ybb[(size_t)(q0 + r) * CC + d] = f2bf(Ov[ci][rg] * invl[rg]);
    }
}

// ------------------------------------------------------- proj + residual (fp32, bf16 y in)
__global__ __launch_bounds__(256) void proj_kernel(const float* __restrict__ x,
                                                   const ushort* __restrict__ y, // bf16 [n][512]
                                                   const float* __restrict__ w,
                                                   const float* __restrict__ bias,
                                                   float* __restrict__ out) {
  __shared__ float As[16][68];
  __shared__ float Bs[16][68];
  __shared__ float Ct[64][68];
  const int b  = blockIdx.z;
  const int m0 = blockIdx.x * 64; // n
  const int o0 = blockIdx.y * 64; // out channel
  const int t  = threadIdx.x;
  const int ty = t >> 4, tx = t & 15;
  float acc[4][4] = {};
  const ushort* ybr = y + (size_t)b * NN * CC;

  for (int k0 = 0; k0 < CC; k0 += 16) {
    {
      const int m = t & 63, kb = (t >> 6) * 4;
      const ushort4 av = *(const ushort4*)&ybr[(size_t)(m0 + m) * CC + k0 + kb];
      As[kb + 0][m] = bf2f(av.x); As[kb + 1][m] = bf2f(av.y);
      As[kb + 2][m] = bf2f(av.z); As[kb + 3][m] = bf2f(av.w);
      const float4 wv = *(const float4*)&w[(size_t)(o0 + m) * CC + k0 + kb];
      Bs[kb + 0][m] = wv.x; Bs[kb + 1][m] = wv.y;
      Bs[kb + 2][m] = wv.z; Bs[kb + 3][m] = wv.w;
    }
    __syncthreads();
    #pragma unroll
    for (int k = 0; k < 16; ++k) {
      const float4 av = *(const float4*)&As[k][ty * 4];
      const float4 bv = *(const float4*)&Bs[k][tx * 4];
      const float ar[4] = {av.x, av.y, av.z, av.w};
      const float br[4] = {bv.x, bv.y, bv.z, bv.w};
      #pragma unroll
      for (int i = 0; i < 4; ++i)
        #pragma unroll
        for (int j = 0; j < 4; ++j)
          acc[i][j] += ar[i] * br[j];
    }
    __syncthreads();
  }

  #pragma unroll
  for (int i = 0; i < 4; ++i)
    #pragma unroll
    for (int j = 0; j < 4; ++j)
      Ct[tx * 4 + j][ty * 4 + i] = acc[i][j];
  __syncthreads();

  const int col = t & 63, rq = t >> 6;
  const float* xb = x + (size_t)b * CC * NN;
  float* ob = out + (size_t)b * CC * NN;
  #pragma unroll
  for (int s = 0; s < 16; ++s) {
    const int ol = rq * 16 + s;
    const int oc = o0 + ol;
    const size_t idx = (size_t)oc * NN + m0 + col;
    ob[idx] = Ct[ol][col] + bias[oc] + xb[idx];
  }
}

// ---------------------------------------------------------------- launch
extern "C" void kernel_launch(void* const* d_in, const int* in_sizes, int n_in,
                              void* d_out, int out_size, void* d_ws, size_t ws_size,
                              hipStream_t stream) {
  const float* x      = (const float*)d_in[0];
  const float* gamma  = (const float*)d_in[1];
  const float* beta   = (const float*)d_in[2];
  const float* w_qkv  = (const float*)d_in[3];
  const float* b_qkv  = (const float*)d_in[4];
  const float* w_proj = (const float*)d_in[5];
  const float* b_proj = (const float*)d_in[6];
  float* out = (float*)d_out;

  float*  stats = (float*)d_ws;                                    // 4KB
  ushort* qbuf  = (ushort*)((char*)d_ws + 4096);                   // 16MB each
  ushort* kbuf  = qbuf + (size_t)BB * NN * CC;
  ushort* vbuf  = kbuf + (size_t)BB * NN * CC;
  ushort* ybuf  = vbuf + (size_t)BB * NN * CC;

  hipLaunchKernelGGL(gn_stats_kernel, dim3(BB * NG), dim3(256), 0, stream, x, stats);
  hipLaunchKernelGGL(qkv_gemm_kernel, dim3(NN / 64, 1536 / 64, BB), dim3(256), 0, stream,
                     x, stats, gamma, beta, w_qkv, b_qkv, qbuf, kbuf, vbuf);
  hipLaunchKernelGGL(attn_mfma_kernel, dim3(NN / 32, BB), dim3(256), 0, stream,
                     qbuf, kbuf, vbuf, ybuf);
  hipLaunchKernelGGL(proj_kernel, dim3(NN / 64, CC / 64, BB), dim3(256), 0, stream,
                     x, ybuf, w_proj, b_proj, out);
}

// Round 12
// 252.866 us; speedup vs baseline: 6.8593x; 2.7209x over previous
//
#include <hip/hip_runtime.h>
#include <cmath>

// NonLocalBlock: GN -> QKV(1x1) -> softmax(QK^T/sqrt(C))V -> proj -> +x
// B=16, C=512, H=W=32, N=1024, G=32 (16 ch/group), fp32 in/out.
//
// Round 11 (= round 6..10 design, unchanged; never yet benched): MFMA everywhere.
//   k1 gn_stats   : per-(b,g) mean/rstd -> ws.stats
//   k1b xn_kernel : x [b][c][n] fp32 -> xnbuf [b][n][c] bf16 (GN fused, LDS transpose)
//   k1c wconv     : w_qkv/w_proj fp32 -> bf16
//   k2 gemm<0>    : xnbuf x w_qkv^T -> qbuf(scaled)/kbuf [b][n][512], vbuf [b][d][n]
//   k3 attn_mfma  : flash, QBLK=32/KBLK=128, mfma 32x32x16 (validated r5: absmax 0.03125)
//   k4 gemm<1>    : ybuf x w_proj^T + bias + x -> out [b][c][n] fp32
// GEMM: 128x128 tile, BK=64, 4 waves x (64x64), mfma_f32_16x16x32_bf16,
//       global_load_lds w=16 with XOR granule pre-swizzle (linear LDS dest,
//       inverse-swizzled source, swizzled ds_read -- rule #21).

#define BB 16
#define CC 512
#define NN 1024
#define NG 32
#define CPG 16
#define EPSV 1e-6f
#define SCALE 0.044194173824159216f  // 1/sqrt(512)

typedef __attribute__((ext_vector_type(8))) short short8;
typedef __attribute__((ext_vector_type(16))) float f32x16;
typedef __attribute__((ext_vector_type(4))) float f32x4;

static __device__ __forceinline__ ushort f2bf(float f) {
  uint32_t x = __float_as_uint(f);
  uint32_t r = (x + 0x7fffu + ((x >> 16) & 1u)) >> 16;  // RNE
  return (ushort)r;
}
static __device__ __forceinline__ float bf2f(ushort u) {
  return __uint_as_float(((uint32_t)u) << 16);
}

// ---------------------------------------------------------------- gn stats
__global__ __launch_bounds__(256) void gn_stats_kernel(const float* __restrict__ x,
                                                       float* __restrict__ stats) {
  const int bg = blockIdx.x;
  const int t  = threadIdx.x;
  const float4* xp = (const float4*)(x + (size_t)bg * (CPG * NN));
  float s = 0.f, ss = 0.f;
  #pragma unroll
  for (int it = 0; it < (CPG * NN / 4) / 256; ++it) {
    float4 v = xp[it * 256 + t];
    s  += v.x + v.y + v.z + v.w;
    ss += v.x * v.x + v.y * v.y + v.z * v.z + v.w * v.w;
  }
  #pragma unroll
  for (int off = 32; off >= 1; off >>= 1) {
    s  += __shfl_down(s, off);
    ss += __shfl_down(ss, off);
  }
  __shared__ float red[4][2];
  if ((t & 63) == 0) { red[t >> 6][0] = s; red[t >> 6][1] = ss; }
  __syncthreads();
  if (t == 0) {
    s  = red[0][0] + red[1][0] + red[2][0] + red[3][0];
    ss = red[0][1] + red[1][1] + red[2][1] + red[3][1];
    const float inv  = 1.f / (float)(CPG * NN);
    const float mean = s * inv;
    const float var  = ss * inv - mean * mean;
    stats[bg * 2 + 0] = mean;
    stats[bg * 2 + 1] = rsqrtf(var + EPSV);
  }
}

// ------------------------------------------------- xn: normalize + transpose to [n][c] bf16
__global__ __launch_bounds__(256) void xn_kernel(const float* __restrict__ x,
                                                 const float* __restrict__ stats,
                                                 const float* __restrict__ gamma,
                                                 const float* __restrict__ beta,
                                                 ushort* __restrict__ xnbuf) {
  __shared__ ushort Tl[64][65];
  const int b  = blockIdx.z;
  const int n0 = blockIdx.x * 64;
  const int c0 = blockIdx.y * 64;
  const int t  = threadIdx.x;
  {
    const int cr = t >> 2, f4 = t & 3;     // 64 c-rows x 4 threads
    const int c  = c0 + cr;
    const float mean = stats[(b * NG + (c >> 4)) * 2 + 0];
    const float rstd = stats[(b * NG + (c >> 4)) * 2 + 1];
    const float ga = gamma[c], be = beta[c];
    const float4* src = (const float4*)(x + ((size_t)b * CC + c) * NN + n0) + f4 * 4;
    #pragma unroll
    for (int j = 0; j < 4; ++j) {
      const float4 v = src[j];
      const int nn = f4 * 16 + j * 4;
      Tl[cr][nn + 0] = f2bf((v.x - mean) * rstd * ga + be);
      Tl[cr][nn + 1] = f2bf((v.y - mean) * rstd * ga + be);
      Tl[cr][nn + 2] = f2bf((v.z - mean) * rstd * ga + be);
      Tl[cr][nn + 3] = f2bf((v.w - mean) * rstd * ga + be);
    }
  }
  __syncthreads();
  {
    const int nr = t >> 2, s = t & 3;      // 64 n-rows x 4 threads, 16 c each
    ushort* dst = xnbuf + ((size_t)b * NN + n0 + nr) * CC + c0 + s * 16;
    #pragma unroll
    for (int u = 0; u < 2; ++u) {
      short8 o;
      #pragma unroll
      for (int e = 0; e < 8; ++e) o[e] = (short)Tl[s * 16 + u * 8 + e][nr];
      *(short8*)(dst + u * 8) = o;
    }
  }
}

// ------------------------------------------------- weight fp32 -> bf16
__global__ __launch_bounds__(256) void wconv_kernel(const float* __restrict__ wq,
                                                    const float* __restrict__ wp,
                                                    ushort* __restrict__ wqb,
                                                    ushort* __restrict__ wpb) {
  const size_t idx = (size_t)blockIdx.x * 256 + threadIdx.x;
  const size_t e = idx * 8;
  const size_t total1 = (size_t)1536 * 512;
  const float* src;
  ushort* dst;
  size_t off;
  if (e < total1) { src = wq; dst = wqb; off = e; }
  else            { src = wp; dst = wpb; off = e - total1; }
  const float4 v0 = *(const float4*)(src + off);
  const float4 v1 = *(const float4*)(src + off + 4);
  short8 o;
  o[0] = (short)f2bf(v0.x); o[1] = (short)f2bf(v0.y);
  o[2] = (short)f2bf(v0.z); o[3] = (short)f2bf(v0.w);
  o[4] = (short)f2bf(v1.x); o[5] = (short)f2bf(v1.y);
  o[6] = (short)f2bf(v1.z); o[7] = (short)f2bf(v1.w);
  *(short8*)(dst + off) = o;
}

// ------------------------------------------------- bf16 MFMA GEMM (m97-style)
// C[128 m][128 o] = A[128 m][512] . W[128 o][512]^T ; BK=64, 8 K-steps.
// LDS tiles [128 rows][64 k] bf16; granule XOR swizzle g' = g ^ (row&7).
__device__ __forceinline__ void stage_tile64(const ushort* __restrict__ src,
                                             ushort* lds, int w, int lane) {
  #pragma unroll
  for (int i = 0; i < 4; ++i) {
    const int ii  = i * 4 + w;                    // 16 instrs per tile
    const int row = ii * 8 + (lane >> 3);
    const int sg  = (lane & 7) ^ (lane >> 3);     // inverse-swizzled source granule
    __builtin_amdgcn_global_load_lds(
        (const __attribute__((address_space(1))) void*)(src + (size_t)row * 512 + sg * 8),
        (__attribute__((address_space(3))) void*)(lds + ii * 512),
        16, 0, 0);
  }
}

template <int MODE>  // 0 = qkv (bf16 q/k/v-planes out), 1 = proj (+bias+residual fp32 out)
__global__ __launch_bounds__(256, 3) void gemm_mfma_kernel(const ushort* __restrict__ A,
                                                           const ushort* __restrict__ W,
                                                           const float* __restrict__ bias,
                                                           const float* __restrict__ xres,
                                                           ushort* __restrict__ qbuf,
                                                           ushort* __restrict__ kbuf,
                                                           ushort* __restrict__ vbuf,
                                                           float* __restrict__ out) {
  __shared__ ushort As[128 * 64];
  __shared__ ushort Bs[128 * 64];
  const int b  = blockIdx.z;
  const int m0 = blockIdx.x * 128;
  const int o0 = blockIdx.y * 128;
  const int t  = threadIdx.x;
  const int lane = t & 63;
  const int w  = t >> 6;
  const int wr = w >> 1, wc = w & 1;     // wave sub-tile (64x64)
  const int lf = lane & 15;              // frag row/col within 16
  const int qw = lane >> 4;              // k-group / C-row group

  const ushort* Ab = A + ((size_t)b * NN + m0) * CC;
  const ushort* Wb = W + (size_t)o0 * CC;

  f32x4 acc[4][4];
  #pragma unroll
  for (int mf = 0; mf < 4; ++mf)
    #pragma unroll
    for (int nf = 0; nf < 4; ++nf)
      #pragma unroll
      for (int r = 0; r < 4; ++r) acc[mf][nf][r] = 0.f;

  for (int k0 = 0; k0 < CC; k0 += 64) {
    __syncthreads();                      // protect previous tile's readers
    stage_tile64(Ab + k0, As, w, lane);
    stage_tile64(Wb + k0, Bs, w, lane);
    __syncthreads();                      // vmcnt drained by compiler
    #pragma unroll
    for (int kk = 0; kk < 2; ++kk) {
      short8 af[4], bf[4];
      #pragma unroll
      for (int mf = 0; mf < 4; ++mf) {
        const int row = wr * 64 + mf * 16 + lf;
        const int g   = ((kk << 2) | qw) ^ (row & 7);
        af[mf] = *(const short8*)((const char*)As + row * 128 + g * 16);
      }
      #pragma unroll
      for (int nf = 0; nf < 4; ++nf) {
        const int row = wc * 64 + nf * 16 + lf;
        const int g   = ((kk << 2) | qw) ^ (row & 7);
        bf[nf] = *(const short8*)((const char*)Bs + row * 128 + g * 16);
      }
      #pragma unroll
      for (int mf = 0; mf < 4; ++mf)
        #pragma unroll
        for (int nf = 0; nf < 4; ++nf)
          acc[mf][nf] = __builtin_amdgcn_mfma_f32_16x16x32_bf16(af[mf], bf[nf], acc[mf][nf], 0, 0, 0);
    }
  }

  // epilogue: C col = o0+wc*64+nf*16+lf, row = m0+wr*64+mf*16+qw*4+r
  float bv[4];
  #pragma unroll
  for (int nf = 0; nf < 4; ++nf) bv[nf] = bias[o0 + wc * 64 + nf * 16 + lf];

  if (MODE == 0) {
    if (o0 < 1024) {  // q or k plane [n][512], q pre-scaled
      ushort* plane = (o0 < 512 ? qbuf : kbuf) + (size_t)b * NN * CC;
      const int oo = (o0 < 512 ? o0 : o0 - 512) + wc * 64;
      const float sc = (o0 < 512) ? SCALE : 1.f;
      #pragma unroll
      for (int mf = 0; mf < 4; ++mf)
        #pragma unroll
        for (int r = 0; r < 4; ++r) {
          const int n = m0 + wr * 64 + mf * 16 + qw * 4 + r;
          #pragma unroll
          for (int nf = 0; nf < 4; ++nf)
            plane[(size_t)n * CC + oo + nf * 16 + lf] = f2bf((acc[mf][nf][r] + bv[nf]) * sc);
        }
    } else {          // v plane transposed [d][n]
      ushort* vb = vbuf + (size_t)b * CC * NN;
      #pragma unroll
      for (int nf = 0; nf < 4; ++nf) {
        const int d = o0 - 1024 + wc * 64 + nf * 16 + lf;
        #pragma unroll
        for (int mf = 0; mf < 4; ++mf)
          #pragma unroll
          for (int r = 0; r < 4; ++r) {
            const int n = m0 + wr * 64 + mf * 16 + qw * 4 + r;
            vb[(size_t)d * NN + n] = f2bf(acc[mf][nf][r] + bv[nf]);
          }
      }
    }
  } else {            // proj: out[oc][n] = acc + bias + x
    const float* xb = xres + (size_t)b * CC * NN;
    float* ob = out + (size_t)b * CC * NN;
    #pragma unroll
    for (int nf = 0; nf < 4; ++nf) {
      const int oc = o0 + wc * 64 + nf * 16 + lf;
      #pragma unroll
      for (int mf = 0; mf < 4; ++mf)
        #pragma unroll
        for (int r = 0; r < 4; ++r) {
          const int n = m0 + wr * 64 + mf * 16 + qw * 4 + r;
          const size_t idx = (size_t)oc * NN + n;
          ob[idx] = acc[mf][nf][r] + bv[nf] + xb[idx];
        }
    }
  }
}

// ------------------------------------------------------------- flash attention (MFMA)
// (unchanged -- hardware-validated r5: passed, absmax 0.03125)
__device__ __forceinline__ void stage_chunk(const ushort* __restrict__ src, int stride,
                                            ushort* kv, int w, int lane) {
  #pragma unroll
  for (int i = 0; i < 8; ++i) {
    const int base = (i * 4 + w) * 1024;                 // bytes, wave-uniform
    const int r    = (base >> 8) + (lane >> 4);          // row 0..127
    const int sx   = ((lane & 15) << 4) ^ ((r & 15) << 4);
    __builtin_amdgcn_global_load_lds(
        (const __attribute__((address_space(1))) void*)(src + (size_t)r * stride + (sx >> 1)),
        (__attribute__((address_space(3))) void*)(kv + (base >> 1)),
        16, 0, 0);
  }
}

__global__ __launch_bounds__(256, 2) void attn_mfma_kernel(const ushort* __restrict__ qb,
                                                           const ushort* __restrict__ kb,
                                                           const ushort* __restrict__ vb,
                                                           ushort* __restrict__ yb) {
  __shared__ ushort KV[128 * 128];   // 32KB chunk
  __shared__ float  Sl[32][132];
  __shared__ ushort Pl[32][136];
  __shared__ float  m_s[32], l_s[32], c_s[32];

  const int orig = blockIdx.x + blockIdx.y * gridDim.x;   // 0..511
  const int wg   = (orig & 7) * 64 + (orig >> 3);
  const int b    = wg >> 5;
  const int q0   = (wg & 31) * 32;
  const int t    = threadIdx.x;
  const int lane = t & 63;
  const int w    = t >> 6;
  const int lr   = lane & 31;
  const int lh   = lane >> 5;

  const ushort* qbb = qb + (size_t)b * NN * CC;
  const ushort* kbb = kb + (size_t)b * NN * CC;
  const ushort* vbb = vb + (size_t)b * CC * NN;
  ushort* ybb = yb + (size_t)b * NN * CC;

  if (t < 32) { m_s[t] = -INFINITY; l_s[t] = 0.f; }

  short8 qf[32];
  #pragma unroll
  for (int f = 0; f < 32; ++f)
    qf[f] = *(const short8*)&qbb[(size_t)(q0 + lr) * CC + f * 16 + lh * 8];

  f32x16 Ov[4];
  #pragma unroll
  for (int ci = 0; ci < 4; ++ci)
    #pragma unroll
    for (int rg = 0; rg < 16; ++rg) Ov[ci][rg] = 0.f;

  for (int k0 = 0; k0 < NN; k0 += 128) {
    f32x16 S;
    #pragma unroll
    for (int rg = 0; rg < 16; ++rg) S[rg] = 0.f;
    #pragma unroll
    for (int cc = 0; cc < 4; ++cc) {
      __syncthreads();
      stage_chunk(kbb + (size_t)k0 * CC + cc * 128, CC, KV, w, lane);
      __syncthreads();
      const int krow = w * 32 + lr;
      #pragma unroll
      for (int cs = 0; cs < 8; ++cs) {
        const int boff = (krow << 8) + ((((cs * 16 + lh * 8) << 1)) ^ ((krow & 15) << 4));
        short8 kf = *(const short8*)((const char*)KV + boff);
        S = __builtin_amdgcn_mfma_f32_32x32x16_bf16(qf[cc * 8 + cs], kf, S, 0, 0, 0);
      }
    }
    #pragma unroll
    for (int rg = 0; rg < 16; ++rg) {
      const int r = (rg & 3) + 8 * (rg >> 2) + 4 * lh;
      Sl[r][w * 32 + lr] = S[rg];
    }
    __syncthreads();
    {
      const int row = t >> 3, seg = t & 7;
      float v[16];
      float mx = -INFINITY;
      #pragma unroll
      for (int u = 0; u < 16; ++u) { v[u] = Sl[row][seg * 16 + u]; mx = fmaxf(mx, v[u]); }
      mx = fmaxf(mx, __shfl_xor(mx, 1));
      mx = fmaxf(mx, __shfl_xor(mx, 2));
      mx = fmaxf(mx, __shfl_xor(mx, 4));
      const float mo = m_s[row];
      const float mn = fmaxf(mo, mx);
      const float corr = __expf(mo - mn);
      float ps = 0.f;
      #pragma unroll
      for (int u = 0; u < 16; ++u) {
        const float p = __expf(v[u] - mn);
        ps += p;
        Pl[row][seg * 16 + u] = f2bf(p);
      }
      ps += __shfl_xor(ps, 1);
      ps += __shfl_xor(ps, 2);
      ps += __shfl_xor(ps, 4);
      if (seg == 0) {
        c_s[row] = corr;
        m_s[row] = mn;
        l_s[row] = l_s[row] * corr + ps;
      }
    }
    __syncthreads();
    float cr[16];
    #pragma unroll
    for (int rg = 0; rg < 16; ++rg) cr[rg] = c_s[(rg & 3) + 8 * (rg >> 2) + 4 * lh];
    #pragma unroll
    for (int ci = 0; ci < 4; ++ci)
      #pragma unroll
      for (int rg = 0; rg < 16; ++rg) Ov[ci][rg] *= cr[rg];
    #pragma unroll
    for (int ci = 0; ci < 4; ++ci) {
      __syncthreads();
      stage_chunk(vbb + (size_t)(ci * 128) * NN + k0, NN, KV, w, lane);
      __syncthreads();
      const int vrow = w * 32 + lr;
      #pragma unroll
      for (int ks = 0; ks < 8; ++ks) {
        short8 pf = *(const short8*)((const char*)Pl + lr * 272 + ks * 32 + lh * 16);
        const int boff = (vrow << 8) + ((((ks * 16 + lh * 8) << 1)) ^ ((vrow & 15) << 4));
        short8 vf = *(const short8*)((const char*)KV + boff);
        Ov[ci] = __builtin_amdgcn_mfma_f32_32x32x16_bf16(pf, vf, Ov[ci], 0, 0, 0);
      }
    }
  }

  float invl[16];
  #pragma unroll
  for (int rg = 0; rg < 16; ++rg) invl[rg] = 1.f / l_s[(rg & 3) + 8 * (rg >> 2) + 4 * lh];
  #pragma unroll
  for (int ci = 0; ci < 4; ++ci)
    #pragma unroll
    for (int rg = 0; rg < 16; ++rg) {
      const int r = (rg & 3) + 8 * (rg >> 2) + 4 * lh;
      const int d = ci * 128 + w * 32 + lr;
      ybb[(size_t)(q0 + r) * CC + d] = f2bf(Ov[ci][rg] * invl[rg]);
    }
}

// ---------------------------------------------------------------- launch
extern "C" void kernel_launch(void* const* d_in, const int* in_sizes, int n_in,
                              void* d_out, int out_size, void* d_ws, size_t ws_size,
                              hipStream_t stream) {
  const float* x      = (const float*)d_in[0];
  const float* gamma  = (const float*)d_in[1];
  const float* beta   = (const float*)d_in[2];
  const float* w_qkv  = (const float*)d_in[3];
  const float* b_qkv  = (const float*)d_in[4];
  const float* w_proj = (const float*)d_in[5];
  const float* b_proj = (const float*)d_in[6];
  float* out = (float*)d_out;

  const size_t PL = (size_t)BB * NN * CC;          // 8M ushorts per plane
  float*  stats = (float*)d_ws;                                    // 4KB
  ushort* xnbuf = (ushort*)((char*)d_ws + 4096);
  ushort* qbuf  = xnbuf + PL;
  ushort* kbuf  = qbuf + PL;
  ushort* vbuf  = kbuf + PL;
  ushort* ybuf  = vbuf + PL;
  ushort* wqb   = ybuf + PL;                        // [1536][512] bf16
  ushort* wpb   = wqb + (size_t)1536 * 512;         // [512][512] bf16

  hipLaunchKernelGGL(gn_stats_kernel, dim3(BB * NG), dim3(256), 0, stream, x, stats);
  hipLaunchKernelGGL(xn_kernel, dim3(NN / 64, CC / 64, BB), dim3(256), 0, stream,
                     x, stats, gamma, beta, xnbuf);
  hipLaunchKernelGGL(wconv_kernel, dim3(512), dim3(256), 0, stream,
                     w_qkv, w_proj, wqb, wpb);
  hipLaunchKernelGGL((gemm_mfma_kernel<0>), dim3(NN / 128, 1536 / 128, BB), dim3(256), 0, stream,
                     xnbuf, wqb, b_qkv, nullptr, qbuf, kbuf, vbuf, nullptr);
  hipLaunchKernelGGL(attn_mfma_kernel, dim3(NN / 32, BB), dim3(256), 0, stream,
                     qbuf, kbuf, vbuf, ybuf);
  hipLaunchKernelGGL((gemm_mfma_kernel<1>), dim3(NN / 128, CC / 128, BB), dim3(256), 0, stream,
                     ybuf, wpb, b_proj, x, nullptr, nullptr, nullptr, out);
}